// Round 8
// baseline (388.515 us; speedup 1.0000x reference)
//
#include <hip/hip_runtime.h>
#include <hip/hip_bf16.h>
#include <stdint.h>

typedef __attribute__((ext_vector_type(8))) short short8;
typedef __attribute__((ext_vector_type(4))) short short4v;
typedef __attribute__((ext_vector_type(4))) float f32x4;

#define HEADS 16
#define HDIM  128
#define BB    2
#define TT    2048
#define DMODEL 2048
#define INNER 2048
#define E3    6144
#define NTOK  (BB*TT)

__device__ inline short bfbits(float v) {
  __hip_bfloat16 h = __float2bfloat16(v);
  return *(short*)&h;
}

// async global->LDS, 16 B per lane. LDS dest is wave-uniform base + lane*16.
__device__ inline void gl_lds16(const __hip_bfloat16* g, __hip_bfloat16* l) {
  __builtin_amdgcn_global_load_lds(
      (const __attribute__((address_space(1))) void*)g,
      (__attribute__((address_space(3))) void*)l, 16, 0, 0);
}

__device__ inline void cvt8(const float* in, __hip_bfloat16* out, int i) {
  float4 a = *(const float4*)(in + i);
  float4 b = *(const float4*)(in + i + 4);
  short8 r;
  r[0]=bfbits(a.x); r[1]=bfbits(a.y); r[2]=bfbits(a.z); r[3]=bfbits(a.w);
  r[4]=bfbits(b.x); r[5]=bfbits(b.y); r[6]=bfbits(b.z); r[7]=bfbits(b.w);
  *(short8*)(out + i) = r;
}

// ---------------------------------------------------------------------------
// prep: cvt x->bf16 (4096 blocks), cvt Wqkv->bf16 (6144 blocks),
//       fill rope table cos/sin (512 blocks). One launch.
// ---------------------------------------------------------------------------
#define NBX   (NTOK*DMODEL/2048)    // 4096
#define NBW   (E3*DMODEL/2048)      // 6144
#define NBT   (TT*64/256)           // 512
__global__ __launch_bounds__(256)
void prep(const float* __restrict__ x, const float* __restrict__ Wqkv,
          __hip_bfloat16* __restrict__ xb, __hip_bfloat16* __restrict__ Wqkvb,
          float2* __restrict__ tab)
{
  const int tid = threadIdx.x;
  int blk = blockIdx.x;
  if (blk < NBX) {
    cvt8(x, xb, (blk*256 + tid)*8);
  } else if (blk < NBX + NBW) {
    cvt8(Wqkv, Wqkvb, ((blk-NBX)*256 + tid)*8);
  } else {
    int idx = (blk - NBX - NBW)*256 + tid;   // 0..131071
    int t  = idx >> 6;
    int d2 = idx & 63;
    float inv = powf(10000.f, -(float)d2 * (1.f/64.f));
    float ang = (float)t * inv;
    tab[idx] = make_float2(cosf(ang), sinf(ang));
  }
}

// ---------------------------------------------------------------------------
// fp32 -> bf16 pack, 8 elems/thread (for Wproj, after gemm_qkv frees its slot)
// ---------------------------------------------------------------------------
__global__ __launch_bounds__(256)
void cvt_bf16(const float* __restrict__ in, __hip_bfloat16* __restrict__ out, int n)
{
  int i = (blockIdx.x * 256 + threadIdx.x) * 8;
  if (i >= n) return;
  cvt8(in, out, i);
}

// ---------------------------------------------------------------------------
// QKV GEMM, 128x256 tile, 8-wave, BK=64, 2-phase K-tile schedule.
// (byte-identical to R2's gemm_qkv3 — best measured: 126-133 us)
// ---------------------------------------------------------------------------
__global__ __launch_bounds__(512, 2)
void gemm_qkv3(const __hip_bfloat16* __restrict__ A,
               const __hip_bfloat16* __restrict__ B,
               const float2* __restrict__ tab,
               __hip_bfloat16* __restrict__ Qh,
               __hip_bfloat16* __restrict__ Kh,
               __hip_bfloat16* __restrict__ Vt)
{
  __shared__ __align__(128) __hip_bfloat16 smem[49152];   // 96 KiB
  const int tid  = threadIdx.x;
  const int lane = tid & 63;
  const int w    = tid >> 6;        // wave 0..7
  const int lm   = lane & 15;
  const int quad = lane >> 4;
  const int wm   = w >> 2;          // 0..1  (M half: 64 rows)
  const int wn   = w & 3;           // 0..3  (N quarter: 64 cols)

  const int flat  = blockIdx.x;
  const int wgid  = (flat & 7) * 96 + (flat >> 3);
  const int tileN = wgid >> 5;      // 0..23
  const int tileM = wgid & 31;      // 0..31
  const int bm    = tileM << 7;     // 128-row tiles
  const int bn    = tileN << 8;     // 256-col tiles
  const int type  = bn >> 11;       // 0=Q 1=K 2=V

  const int r0 = tid >> 3;                  // row within 64-row chunk
  const int kc = (tid & 7) ^ (r0 & 7);      // inverse-swizzled k-chunk
  const size_t gA0 = ((size_t)(bm      + r0) << 11) + kc*8;
  const size_t gA1 = ((size_t)(bm + 64 + r0) << 11) + kc*8;
  size_t gB[2][2];
  #pragma unroll
  for (int h = 0; h < 2; ++h)
    #pragma unroll
    for (int j = 0; j < 2; ++j) {
      int prow;
      if (type < 2)   // RoPE-pair permutation (bijective bit shuffle)
        prow = h*128 + j*32 + ((r0 >> 5) << 6) + (((r0 >> 4) & 1) << 4) + (r0 & 15);
      else            // identity for V
        prow = h*128 + j*64 + r0;
      gB[h][j] = ((size_t)(bn + prow) << 11) + kc*8;
    }
  const int ldsW = w * 512;         // wave-uniform lane-group base (elements)

#define STAGE_A(ktt, bb_) do { \
    __hip_bfloat16* _l = smem + (bb_)*24576 + ldsW; \
    gl_lds16(A + gA0 + (size_t)(ktt)*64, _l); \
    gl_lds16(A + gA1 + (size_t)(ktt)*64, _l + 4096); \
  } while (0)
#define STAGE_B(h, ktt, bb_) do { \
    __hip_bfloat16* _l = smem + (bb_)*24576 + 8192 + (h)*8192 + ldsW; \
    gl_lds16(B + gB[h][0] + (size_t)(ktt)*64, _l); \
    gl_lds16(B + gB[h][1] + (size_t)(ktt)*64, _l + 4096); \
  } while (0)

  const int xk0 = ((quad      ^ (lm & 7)) << 3);   // k_sub 0
  const int xk1 = (((quad|4)  ^ (lm & 7)) << 3);   // k_sub 1
  const int aRow = wm*4096 + lm*64;                            // + f*1024
  const int bRow = 8192 + (wn>>1)*8192 + (wn&1)*4096 + lm*64;  // + f*1024

  f32x4 acc[4][4];
  #pragma unroll
  for (int i=0;i<4;i++)
    #pragma unroll
    for (int j=0;j<4;j++) acc[i][j] = (f32x4){0.f,0.f,0.f,0.f};

  STAGE_A(0, 0);
  STAGE_B(0, 0, 0);
  STAGE_B(1, 0, 0);
  STAGE_A(1, 1);
  asm volatile("s_waitcnt vmcnt(2)" ::: "memory");
  __builtin_amdgcn_s_barrier();

  #pragma unroll 2
  for (int kt = 0; kt < 32; ++kt) {
    const int cb   = kt & 1;
    const int nb   = cb ^ 1;
    const int cOff = cb * 24576;

    short8 a0[4], b0[4], a1[4], b1[4];
    #pragma unroll
    for (int f = 0; f < 4; ++f) {
      a0[f] = *(const short8*)(smem + cOff + aRow + f*1024 + xk0);
      b0[f] = *(const short8*)(smem + cOff + bRow + f*1024 + xk0);
    }
    #pragma unroll
    for (int f = 0; f < 4; ++f) {
      a1[f] = *(const short8*)(smem + cOff + aRow + f*1024 + xk1);
      b1[f] = *(const short8*)(smem + cOff + bRow + f*1024 + xk1);
    }
    if (kt + 1 < 32) STAGE_B(0, kt+1, nb);
    __builtin_amdgcn_s_barrier();
    __builtin_amdgcn_s_setprio(1);
    #pragma unroll
    for (int i = 0; i < 4; ++i)
      #pragma unroll
      for (int j = 0; j < 4; ++j)
        acc[i][j] = __builtin_amdgcn_mfma_f32_16x16x32_bf16(a0[i], b0[j], acc[i][j], 0,0,0);
    __builtin_amdgcn_s_setprio(0);
    __builtin_amdgcn_s_barrier();

    if (kt + 1 < 32) STAGE_B(1, kt+1, nb);
    if (kt + 2 < 32) STAGE_A(kt+2, cb);     // cb A-region fully read at q0
    __builtin_amdgcn_s_barrier();
    __builtin_amdgcn_s_setprio(1);
    #pragma unroll
    for (int i = 0; i < 4; ++i)
      #pragma unroll
      for (int j = 0; j < 4; ++j)
        acc[i][j] = __builtin_amdgcn_mfma_f32_16x16x32_bf16(a1[i], b1[j], acc[i][j], 0,0,0);
    __builtin_amdgcn_s_setprio(0);
    if (kt < 30) asm volatile("s_waitcnt vmcnt(2)" ::: "memory");
    else         asm volatile("s_waitcnt vmcnt(0)" ::: "memory");
    __builtin_amdgcn_s_barrier();
  }
#undef STAGE_A
#undef STAGE_B

  const float SCQ = 0.08838834764831845f * 1.4426950408889634f;  // scale*log2(e)
  const int tok0 = bm + wm*64;
  if (type < 2) {
    __hip_bfloat16* const dst = (type == 0) ? Qh : Kh;
    const float mul = (type == 0) ? SCQ : 1.0f;
    const int head = ((bn & 2047) >> 7) + (wn >> 1);
    const int d2b  = (wn & 1)*32 + lm;
    #pragma unroll
    for (int i = 0; i < 4; ++i) {
      #pragma unroll
      for (int r = 0; r < 4; ++r) {
        const int t  = tok0 + i*16 + quad*4 + r;
        const int b  = t >> 11;
        const int tl = t & (TT-1);
        const float2* tp = tab + (size_t)tl*64;
        __hip_bfloat16* const o = dst + ((size_t)(b*HEADS + head)*TT + tl)*HDIM;
        #pragma unroll
        for (int j = 0; j < 2; ++j) {
          const int d2 = d2b + j*16;
          const float2 cs = tp[d2];
          const float v1 = acc[i][j  ][r];
          const float v2 = acc[i][j+2][r];
          o[d2]      = __float2bfloat16((v1*cs.x - v2*cs.y) * mul);
          o[d2 + 64] = __float2bfloat16((v2*cs.x + v1*cs.y) * mul);
        }
      }
    }
  } else {
    const int fcb = (bn & 2047) + wn*64 + lm;
    #pragma unroll
    for (int i = 0; i < 4; ++i) {
      const int t0 = tok0 + i*16 + quad*4;
      const int b  = t0 >> 11;
      const int tl = t0 & (TT-1);
      #pragma unroll
      for (int j = 0; j < 4; ++j) {
        const int c    = fcb + j*16;
        const int head = c >> 7;
        const int d    = c & 127;
        short4v o;
        #pragma unroll
        for (int r = 0; r < 4; ++r) o[r] = bfbits(acc[i][j][r]);
        *(short4v*)(Vt + ((size_t)(b*HEADS + head)*HDIM + d)*TT + tl) = o;
      }
    }
  }
}

// ---------------------------------------------------------------------------
// Output projection GEMM (unchanged from R7 — one exact dispatch round).
// ---------------------------------------------------------------------------
__global__ __launch_bounds__(512, 2)
void gemm_proj(const __hip_bfloat16* __restrict__ A,
               const __hip_bfloat16* __restrict__ B,
               float* __restrict__ C)
{
  __shared__ __align__(128) __hip_bfloat16 smem[49152];   // 96 KiB
  const int tid  = threadIdx.x;
  const int lane = tid & 63;
  const int w    = tid >> 6;
  const int lm   = lane & 15;
  const int quad = lane >> 4;
  const int wm   = w >> 2;
  const int wn   = w & 3;

  const int flat  = blockIdx.x;
  const int wgid  = (flat & 7) * 32 + (flat >> 3);
  const int tileN = wgid >> 5;      // 0..7
  const int tileM = wgid & 31;      // 0..31
  const int bm    = tileM << 7;
  const int bn    = tileN << 8;

  const int r0 = tid >> 3;
  const int kc = (tid & 7) ^ (r0 & 7);
  const size_t gA0 = ((size_t)(bm      + r0) << 11) + kc*8;
  const size_t gA1 = ((size_t)(bm + 64 + r0) << 11) + kc*8;
  size_t gB[2][2];
  #pragma unroll
  for (int h = 0; h < 2; ++h)
    #pragma unroll
    for (int j = 0; j < 2; ++j)
      gB[h][j] = ((size_t)(bn + h*128 + j*64 + r0) << 11) + kc*8;
  const int ldsW = w * 512;

#define STAGE_A(ktt, bb_) do { \
    __hip_bfloat16* _l = smem + (bb_)*24576 + ldsW; \
    gl_lds16(A + gA0 + (size_t)(ktt)*64, _l); \
    gl_lds16(A + gA1 + (size_t)(ktt)*64, _l + 4096); \
  } while (0)
#define STAGE_B(h, ktt, bb_) do { \
    __hip_bfloat16* _l = smem + (bb_)*24576 + 8192 + (h)*8192 + ldsW; \
    gl_lds16(B + gB[h][0] + (size_t)(ktt)*64, _l); \
    gl_lds16(B + gB[h][1] + (size_t)(ktt)*64, _l + 4096); \
  } while (0)

  const int xk0 = ((quad      ^ (lm & 7)) << 3);
  const int xk1 = (((quad|4)  ^ (lm & 7)) << 3);
  const int aRow = wm*4096 + lm*64;
  const int bRow = 8192 + (wn>>1)*8192 + (wn&1)*4096 + lm*64;

  f32x4 acc[4][4];
  #pragma unroll
  for (int i=0;i<4;i++)
    #pragma unroll
    for (int j=0;j<4;j++) acc[i][j] = (f32x4){0.f,0.f,0.f,0.f};

  STAGE_A(0, 0);
  STAGE_B(0, 0, 0);
  STAGE_B(1, 0, 0);
  STAGE_A(1, 1);
  asm volatile("s_waitcnt vmcnt(2)" ::: "memory");
  __builtin_amdgcn_s_barrier();

  #pragma unroll 2
  for (int kt = 0; kt < 32; ++kt) {
    const int cb   = kt & 1;
    const int nb   = cb ^ 1;
    const int cOff = cb * 24576;

    short8 a0[4], b0[4], a1[4], b1[4];
    #pragma unroll
    for (int f = 0; f < 4; ++f) {
      a0[f] = *(const short8*)(smem + cOff + aRow + f*1024 + xk0);
      b0[f] = *(const short8*)(smem + cOff + bRow + f*1024 + xk0);
    }
    #pragma unroll
    for (int f = 0; f < 4; ++f) {
      a1[f] = *(const short8*)(smem + cOff + aRow + f*1024 + xk1);
      b1[f] = *(const short8*)(smem + cOff + bRow + f*1024 + xk1);
    }
    if (kt + 1 < 32) STAGE_B(0, kt+1, nb);
    __builtin_amdgcn_s_barrier();
    __builtin_amdgcn_s_setprio(1);
    #pragma unroll
    for (int i = 0; i < 4; ++i)
      #pragma unroll
      for (int j = 0; j < 4; ++j)
        acc[i][j] = __builtin_amdgcn_mfma_f32_16x16x32_bf16(a0[i], b0[j], acc[i][j], 0,0,0);
    __builtin_amdgcn_s_setprio(0);
    __builtin_amdgcn_s_barrier();

    if (kt + 1 < 32) STAGE_B(1, kt+1, nb);
    if (kt + 2 < 32) STAGE_A(kt+2, cb);
    __builtin_amdgcn_s_barrier();
    __builtin_amdgcn_s_setprio(1);
    #pragma unroll
    for (int i = 0; i < 4; ++i)
      #pragma unroll
      for (int j = 0; j < 4; ++j)
        acc[i][j] = __builtin_amdgcn_mfma_f32_16x16x32_bf16(a1[i], b1[j], acc[i][j], 0,0,0);
    __builtin_amdgcn_s_setprio(0);
    if (kt < 30) asm volatile("s_waitcnt vmcnt(2)" ::: "memory");
    else         asm volatile("s_waitcnt vmcnt(0)" ::: "memory");
    __builtin_amdgcn_s_barrier();
  }
#undef STAGE_A
#undef STAGE_B

  const int tok0 = bm + wm*64;
  const int coln = bn + wn*64 + lm;
  #pragma unroll
  for (int i = 0; i < 4; ++i)
    #pragma unroll
    for (int j = 0; j < 4; ++j)
      #pragma unroll
      for (int r = 0; r < 4; ++r)
        C[(size_t)(tok0 + i*16 + quad*4 + r)*INNER + coln + j*16] = acc[i][j][r];
}

// ---------------------------------------------------------------------------
// Causal flash attention v5 = v4 math + 2 q-subtiles per wave:
//  - block owns a 128-row q-tile (lo rows q0A..+63, hi rows q0B..+63);
//    every sK read feeds TWO QK^T MFMAs, every sV read feeds TWO PV MFMAs
//    -> LDS instrs/FLOP -44%, KV staging traffic -45%.
//  - LPT pairing: block c (j=15-jl) + block c+256 (j=jl) share bh and a CU
//    slot; combined work = 36 iters for every pair (uniform). XCD-chunked
//    bh decode keeps each bh's KV inside one XCD's L2.
//  - loAct guard (wave-uniform) handles the final diagonal iter where the
//    lo subtile is fully masked. Per-subtile math identical to v4.
// ---------------------------------------------------------------------------
__global__ __launch_bounds__(256, 2)
void flash_attn5(const __hip_bfloat16* __restrict__ Qh,
                 const __hip_bfloat16* __restrict__ Kh,
                 const __hip_bfloat16* __restrict__ Vt,
                 __hip_bfloat16* __restrict__ Out)
{
  const int tid  = threadIdx.x;
  const int lane = tid & 63;
  const int wv   = tid >> 6;
  const int lm   = lane & 15;
  const int quad = lane >> 4;
  // decode: 512 blocks = 2 groups x 256; group0 = long (j=15-jl), group1 =
  // short (j=jl); within a group, XCD-chunk so 4 consecutive bh per XCD.
  const int flat = blockIdx.x;
  const int g    = flat >> 8;
  const int i8   = flat & 255;
  const int idx2 = (i8 & 7) * 32 + (i8 >> 3);
  const int bh   = idx2 >> 3;
  const int jl   = idx2 & 7;
  const int j    = g ? jl : 15 - jl;
  const int b    = bh >> 4;
  const int h    = bh & 15;

  __shared__ __hip_bfloat16 sK[64*136];
  __shared__ __hip_bfloat16 sV[128*72];
  __shared__ __hip_bfloat16 sP[4][16*72];

  const float FML2 = 8.0f * 1.4426950408889634f;

  const int rk0 = tid >> 4;
  const int ck  = (tid & 15) * 8;
  const int dv0 = tid >> 3;
  const int cv  = (tid & 7) * 8;
  const __hip_bfloat16* Kp = Kh + (size_t)bh*TT*HDIM + (size_t)rk0*HDIM + ck;
  const __hip_bfloat16* Vp = Vt + (size_t)bh*HDIM*TT + (size_t)dv0*TT + cv;

  const int q0A = j * 128;          // lo subtile base
  const int q0B = q0A + 64;         // hi subtile base

  short8 aqA[4], aqB[4];
  {
    const __hip_bfloat16* qp = Qh + ((size_t)bh*TT + q0A + wv*16 + lm)*HDIM + quad*8;
    #pragma unroll
    for (int kd=0;kd<4;kd++) {
      aqA[kd] = *(const short8*)(qp + kd*32);
      aqB[kd] = *(const short8*)(qp + (size_t)64*HDIM + kd*32);
    }
  }

  float lA = 0.f, lB = 0.f;
  f32x4 accA[8], accB[8];
  #pragma unroll
  for (int i=0;i<8;i++) { accA[i] = (f32x4){0.f,0.f,0.f,0.f}; accB[i] = (f32x4){0.f,0.f,0.f,0.f}; }

  short8 pk[4], pv[4];
  #pragma unroll
  for (int it=0;it<4;++it) {
    pk[it] = *(const short8*)(Kp + (size_t)it*16*HDIM);
    pv[it] = *(const short8*)(Vp + (size_t)it*32*TT);
  }
  Kp += (size_t)64*HDIM; Vp += 64;

  for (int kv0 = 0; kv0 <= q0B; kv0 += 64) {
    __syncthreads();
    #pragma unroll
    for (int it=0;it<4;++it) {
      *(short8*)(&sK[(it*16 + rk0)*136 + ck]) = pk[it];
      *(short8*)(&sV[(it*32 + dv0)*72 + cv])  = pv[it];
    }
    if (kv0 + 64 <= q0B) {
      #pragma unroll
      for (int it=0;it<4;++it) {
        pk[it] = *(const short8*)(Kp + (size_t)it*16*HDIM);
        pv[it] = *(const short8*)(Vp + (size_t)it*32*TT);
      }
      Kp += (size_t)64*HDIM; Vp += 64;
    }
    __syncthreads();

    const bool loAct = (kv0 <= q0A);

    // ---- QK^T (swapped: A=K, B=Q), shared bk reads ----
    f32x4 sca[4], scb[4];
    #pragma unroll
    for (int nt=0;nt<4;nt++) { sca[nt] = (f32x4){0.f,0.f,0.f,0.f}; scb[nt] = (f32x4){0.f,0.f,0.f,0.f}; }
    __builtin_amdgcn_s_setprio(1);
    if (loAct) {
      #pragma unroll
      for (int kd=0;kd<4;kd++)
        #pragma unroll
        for (int nt=0;nt<4;nt++) {
          short8 bk = *(const short8*)(&sK[(nt*16 + lm)*136 + kd*32 + quad*8]);
          sca[nt] = __builtin_amdgcn_mfma_f32_16x16x32_bf16(bk, aqA[kd], sca[nt], 0,0,0);
          scb[nt] = __builtin_amdgcn_mfma_f32_16x16x32_bf16(bk, aqB[kd], scb[nt], 0,0,0);
        }
    } else {
      #pragma unroll
      for (int kd=0;kd<4;kd++)
        #pragma unroll
        for (int nt=0;nt<4;nt++) {
          short8 bk = *(const short8*)(&sK[(nt*16 + lm)*136 + kd*32 + quad*8]);
          scb[nt] = __builtin_amdgcn_mfma_f32_16x16x32_bf16(bk, aqB[kd], scb[nt], 0,0,0);
        }
    }
    __builtin_amdgcn_s_setprio(0);

    // ---- softmax (fixed-max) + packed sP writes; lo then hi (in-wave order) ----
    short8 apA0, apA1, apB0, apB1;
    if (loAct) {
      const int qc = q0A + wv*16 + lm;
      const bool diag = (kv0 == q0A);
      #pragma unroll
      for (int nt=0;nt<4;nt++) {
        short4v w;
        #pragma unroll
        for (int r=0;r<4;r++) {
          float p = exp2f(sca[nt][r] - FML2);
          if (diag && (kv0 + nt*16 + quad*4 + r > qc)) p = 0.f;
          lA += p;
          w[r] = bfbits(p);
        }
        *(short4v*)(&sP[wv][lm*72 + nt*16 + quad*4]) = w;
      }
      apA0 = *(const short8*)(&sP[wv][lm*72 + quad*8]);
      apA1 = *(const short8*)(&sP[wv][lm*72 + 32 + quad*8]);
    }
    {
      const int qc = q0B + wv*16 + lm;
      const bool diag = (kv0 == q0B);
      #pragma unroll
      for (int nt=0;nt<4;nt++) {
        short4v w;
        #pragma unroll
        for (int r=0;r<4;r++) {
          float p = exp2f(scb[nt][r] - FML2);
          if (diag && (kv0 + nt*16 + quad*4 + r > qc)) p = 0.f;
          lB += p;
          w[r] = bfbits(p);
        }
        *(short4v*)(&sP[wv][lm*72 + nt*16 + quad*4]) = w;
      }
      apB0 = *(const short8*)(&sP[wv][lm*72 + quad*8]);
      apB1 = *(const short8*)(&sP[wv][lm*72 + 32 + quad*8]);
    }

    // ---- PV, shared bvv reads ----
    __builtin_amdgcn_s_setprio(1);
    if (loAct) {
      #pragma unroll
      for (int nt2=0;nt2<8;nt2++) {
        short8 bvv = *(const short8*)(&sV[(nt2*16 + lm)*72 + quad*8]);
        accA[nt2] = __builtin_amdgcn_mfma_f32_16x16x32_bf16(apA0, bvv, accA[nt2], 0,0,0);
        accB[nt2] = __builtin_amdgcn_mfma_f32_16x16x32_bf16(apB0, bvv, accB[nt2], 0,0,0);
      }
      #pragma unroll
      for (int nt2=0;nt2<8;nt2++) {
        short8 bvv = *(const short8*)(&sV[(nt2*16 + lm)*72 + 32 + quad*8]);
        accA[nt2] = __builtin_amdgcn_mfma_f32_16x16x32_bf16(apA1, bvv, accA[nt2], 0,0,0);
        accB[nt2] = __builtin_amdgcn_mfma_f32_16x16x32_bf16(apB1, bvv, accB[nt2], 0,0,0);
      }
    } else {
      #pragma unroll
      for (int nt2=0;nt2<8;nt2++) {
        short8 bvv = *(const short8*)(&sV[(nt2*16 + lm)*72 + quad*8]);
        accB[nt2] = __builtin_amdgcn_mfma_f32_16x16x32_bf16(apB0, bvv, accB[nt2], 0,0,0);
      }
      #pragma unroll
      for (int nt2=0;nt2<8;nt2++) {
        short8 bvv = *(const short8*)(&sV[(nt2*16 + lm)*72 + 32 + quad*8]);
        accB[nt2] = __builtin_amdgcn_mfma_f32_16x16x32_bf16(apB1, bvv, accB[nt2], 0,0,0);
      }
    }
    __builtin_amdgcn_s_setprio(0);
  }

  // ---- denominators + output ----
  lA += __shfl_xor(lA, 16); lA += __shfl_xor(lA, 32);
  lB += __shfl_xor(lB, 16); lB += __shfl_xor(lB, 32);
  const float liA = 1.f / lA;
  const float liB = 1.f / lB;
  float invA[4], invB[4];
  #pragma unroll
  for (int r=0;r<4;r++) { invA[r] = __shfl(liA, quad*4 + r); invB[r] = __shfl(liB, quad*4 + r); }

  #pragma unroll
  for (int nt2=0;nt2<8;nt2++)
    #pragma unroll
    for (int r=0;r<4;r++) {
      const int tA = q0A + wv*16 + quad*4 + r;
      const int tB = q0B + wv*16 + quad*4 + r;
      Out[((size_t)b*TT + tA)*INNER + (size_t)h*HDIM + nt2*16 + lm] =
        __float2bfloat16(accA[nt2][r] * invA[r]);
      Out[((size_t)b*TT + tB)*INNER + (size_t)h*HDIM + nt2*16 + lm] =
        __float2bfloat16(accB[nt2][r] * invB[r]);
    }
}

// ---------------------------------------------------------------------------
extern "C" void kernel_launch(void* const* d_in, const int* in_sizes, int n_in,
                              void* d_out, int out_size, void* d_ws, size_t ws_size,
                              hipStream_t stream)
{
  (void)in_sizes; (void)n_in; (void)out_size; (void)ws_size;
  const float* x     = (const float*)d_in[0];
  const float* Wqkv  = (const float*)d_in[1];
  const float* Wproj = (const float*)d_in[2];
  float* out = (float*)d_out;

  // Workspace (100.66 MB, R3-proven size):
  //  [0, 16.78): xb -> attn_out (xb dead after gemm_qkv)
  //  [16.78, 41.94): Wqkvb -> Wprojb overlay (Wqkvb dead after gemm_qkv)
  //  [41.94, 50.33): rope table (1 MB used; dead after gemm_qkv)
  //  [50.33, 67.11): Qh  [67.11, 83.89): Kh  [83.89, 100.66): Vt
  char* ws = (char*)d_ws;
  __hip_bfloat16* xb       = (__hip_bfloat16*)ws;
  __hip_bfloat16* attn_out = xb;
  char* p1 = ws + (size_t)NTOK*DMODEL*2;
  __hip_bfloat16* Wqkvb  = (__hip_bfloat16*)p1;
  __hip_bfloat16* Wprojb = (__hip_bfloat16*)p1;
  char* p2 = p1 + (size_t)E3*DMODEL*2;
  float2* ropeTab = (float2*)p2;
  char* p3 = p2 + (size_t)DMODEL*INNER*2;   // 8.39 MB slot (table uses 1 MB)
  const size_t hsz = (size_t)BB*HEADS*TT*HDIM*2;
  __hip_bfloat16* Qh = (__hip_bfloat16*)p3;
  __hip_bfloat16* Kh = (__hip_bfloat16*)(p3 + hsz);
  __hip_bfloat16* Vt = (__hip_bfloat16*)(p3 + 2*hsz);

  prep<<<dim3(NBX + NBW + NBT), dim3(256), 0, stream>>>(x, Wqkv, xb, Wqkvb, ropeTab);

  gemm_qkv3<<<dim3(768), dim3(512), 0, stream>>>(xb, Wqkvb, ropeTab, Qh, Kh, Vt);

  // Wqkvb + table dead; overlay Wprojb.
  cvt_bf16<<<dim3(DMODEL*INNER/2048), dim3(256), 0, stream>>>(Wproj, Wprojb, DMODEL*INNER);

  flash_attn5<<<dim3(512), dim3(256), 0, stream>>>(Qh, Kh, Vt, attn_out);

  gemm_proj<<<dim3(256), dim3(512), 0, stream>>>(attn_out, Wprojb, out);
}